// Round 3
// baseline (118.936 us; speedup 1.0000x reference)
//
#include <hip/hip_runtime.h>

// ---------------------------------------------------------------------------
// GeometricSuperpositionSearch (all fp32): the reference collapses to
//   new[b,n,l] = sum_j x[b,n,j] * comb[b][j^l] * sign(j^l, j)
// where comb[b] is a single 16-component multivector per batch:
//   comb[b][i] = sum_k weights[b,k] * scores[b,k] * (templates[k,i] + rule_mod[b,k,i])
// k1: reduce cpu_state over N (partial sums)  -> ws
// k2: tiny (1 block): summary, grade norms, MLP, threefry gumbel, softmax,
//     collapse to comb[8][16]                 -> ws
// k3: apply 16x16 signed-permutation operator to every row (memory-bound)
//
// RNG: jax >= 0.4.30 defaults to jax_threefry_partitionable=True, so
// random_bits(shape=(8,8)) is per-element: counter64 = flat index t,
// (x0,x1) = (hi32=0, lo32=t), bits = y0 ^ y1.  (Round-2 used the legacy
// split-counter stream -> wrong gumbel -> wrong softmax weights.)
// ---------------------------------------------------------------------------

#define B_ 8
#define N_ 65536
#define D_ 16
#define K_ 8
#define M_ 8
#define HID_ 64
#define BLK_PER_B 128                    // k1 blocks per batch
#define ROWS_PER_BLK (N_ / BLK_PER_B)    // 512 rows -> 2048 float4 per slab

// ---- compile-time Cayley sign table: SGN.v[a][b] = sign of e_a * e_b -> e_{a^b}
struct SgnTab { float v[16][16]; };
constexpr SgnTab make_sgn() {
  SgnTab t{};
  for (int a = 0; a < 16; a++)
    for (int b = 0; b < 16; b++) {
      float s = 1.0f;
      for (int i = 0; i < 4; i++)
        if ((b >> i) & 1) {
          int h = a >> (i + 1), pc = 0;
          for (int q = 0; q < 4; q++) pc += (h >> q) & 1;
          if (pc & 1) s = -s;
          if ((a >> i) & 1) s *= (i == 0 ? 0.0f : 1.0f);  // metric {0,1,1,1}
        }
      t.v[a][b] = s;
    }
  return t;
}
constexpr SgnTab SGN = make_sgn();

// ---- threefry2x32-20, exactly as in jax/_src/prng.py ----
__device__ __forceinline__ unsigned rotl32(unsigned x, int n) {
  return (x << n) | (x >> (32 - n));
}
__device__ void threefry2x32(unsigned k0, unsigned k1, unsigned& x0, unsigned& x1) {
  unsigned ks0 = k0, ks1 = k1, ks2 = k0 ^ k1 ^ 0x1BD11BDAu;
  x0 += ks0; x1 += ks1;
  const int rotA[4] = {13, 15, 26, 6};
  const int rotB[4] = {17, 29, 16, 24};
#define TF_R4(rot)                                      \
  _Pragma("unroll")                                     \
  for (int r = 0; r < 4; r++) {                         \
    x0 += x1; x1 = rotl32(x1, rot[r]); x1 ^= x0;        \
  }
  TF_R4(rotA); x0 += ks1; x1 += ks2 + 1u;
  TF_R4(rotB); x0 += ks2; x1 += ks0 + 2u;
  TF_R4(rotA); x0 += ks0; x1 += ks1 + 3u;
  TF_R4(rotB); x0 += ks1; x1 += ks2 + 4u;
  TF_R4(rotA); x0 += ks2; x1 += ks0 + 5u;
#undef TF_R4
}

// ---------------------------------------------------------------------------
// k1: per-(b,d) partial sums of cpu_state over a 512-row slab.
// Fully-coalesced float4 streaming: thread t's flat float4 indices all have
// f&3 == t&3, so it accumulates a fixed component group 4*(t&3)..4*(t&3)+3.
// grid (BLK_PER_B, B_), 256 threads
// ---------------------------------------------------------------------------
__global__ __launch_bounds__(256) void k1_reduce(
    const float* __restrict__ cpu, float* __restrict__ partial) {
  const int b = blockIdx.y, blk = blockIdx.x, t = threadIdx.x;
  const float4* base =
      (const float4*)(cpu + (((size_t)b << 16) + (size_t)blk * ROWS_PER_BLK) * D_);
  float a0 = 0.f, a1 = 0.f, a2 = 0.f, a3 = 0.f;
#pragma unroll
  for (int i = 0; i < (ROWS_PER_BLK * 4) / 256; i++) {   // 8 iters
    float4 v = base[i * 256 + t];
    a0 += v.x; a1 += v.y; a2 += v.z; a3 += v.w;
  }
  __shared__ float red[256 * 4];
  red[t * 4 + 0] = a0; red[t * 4 + 1] = a1;
  red[t * 4 + 2] = a2; red[t * 4 + 3] = a3;
  __syncthreads();
  if (t < 16) {
    const int c = t >> 2, j = t & 3;      // component d = 4c + j
    float s = 0.f;
#pragma unroll
    for (int m = 0; m < 64; m++) s += red[(c + 4 * m) * 4 + j];
    partial[((size_t)b * BLK_PER_B + blk) * 16 + t] = s;
  }
}

// ---------------------------------------------------------------------------
// k2: single block, everything small -> comb[8][16] (fp32)
// ---------------------------------------------------------------------------
__global__ __launch_bounds__(256) void k2_small(
    const float* __restrict__ partial,
    const float* __restrict__ ctrl,      // [8,4]
    const float* __restrict__ rulemem,   // [8,8,16]
    const float* __restrict__ templates, // [8,16]
    const float* __restrict__ W1,        // [9,64]
    const float* __restrict__ b1,        // [64]
    const float* __restrict__ W2,        // [64,8]
    const float* __restrict__ b2,        // [8]
    const float* __restrict__ Wr,        // [16,128]
    const float* __restrict__ br,        // [128]
    const float* __restrict__ logt,      // [1]
    float* __restrict__ comb) {
  const int t = threadIdx.x;
  __shared__ float summary[8][16], rs[8][16], gn[8][5], h[8][64], sc[8][8];
  __shared__ float instr[8][8][16], g64[64], wts[8][8];

  // A: finalize cpu_summary + rule_summary
  if (t < 128) {
    const int b = t >> 4, d = t & 15;
    float s = 0.f;
    for (int i = 0; i < BLK_PER_B; i++)
      s += partial[((size_t)(b * BLK_PER_B + i)) * 16 + d];
    summary[b][d] = s * (1.0f / (float)N_);
    float rsum = 0.f;
    for (int m = 0; m < M_; m++) rsum += rulemem[(b * M_ + m) * 16 + d];
    rs[b][d] = rsum * (1.0f / (float)M_);
  }
  __syncthreads();
  // B: grade norms
  if (t < 40) {
    const int b = t / 5, g = t % 5;
    float s = 0.f;
    for (int d = 0; d < 16; d++)
      if (__popc(d) == g) { float v = summary[b][d]; s += v * v; }
    gn[b][g] = sqrtf(s + 1e-12f);
  }
  __syncthreads();
  // C1: hidden layer [8][64]
  for (int idx = t; idx < B_ * HID_; idx += 256) {
    const int b = idx >> 6, j = idx & 63;
    float a = b1[j];
    for (int i = 0; i < 9; i++) {
      float in = (i < 5) ? gn[b][i] : ctrl[b * 4 + (i - 5)];
      a += in * W1[i * HID_ + j];
    }
    h[b][j] = fmaxf(a, 0.f);
  }
  __syncthreads();
  // C2: scores [8][8]
  if (t < 64) {
    const int b = t >> 3, k = t & 7;
    float a = b2[k];
    for (int j = 0; j < HID_; j++) a += h[b][j] * W2[j * K_ + k];
    sc[b][k] = a;
  }
  __syncthreads();
  // D: instructions [8][8][16] = scores * (templates + rule_mod)
  for (int idx = t; idx < B_ * K_ * 16; idx += 256) {
    const int b = idx >> 7, k = (idx >> 4) & 7, d = idx & 15;
    float a = br[k * 16 + d];
    for (int j = 0; j < 16; j++) a += rs[b][j] * Wr[j * 128 + k * 16 + d];
    instr[b][k][d] = sc[b][k] * (templates[k * 16 + d] + a);
  }
  // E: gumbel noise — partitionable threefry (jax >= 0.4.30 default):
  // element t: counter64 = t -> (x0, x1) = (0, t); bits = y0 ^ y1
  if (t < 64) {
    unsigned x0 = 0u, x1 = (unsigned)t;
    threefry2x32(0u, 42u, x0, x1);   // key(42) = (0, 42)
    unsigned bits = x0 ^ x1;
    float f01 = __uint_as_float((bits >> 9) | 0x3f800000u) - 1.0f;
    float u = fmaxf(1e-6f, f01 * (1.0f - 2e-6f) + 1e-6f);
    g64[t] = -logf(-logf(u));
  }
  __syncthreads();
  // weights: softmax((scores+g)/tau)
  if (t < 8) {
    float lt = logt[0];
    float tau = fminf(fmaxf(expf(lt), 0.1f), 5.0f);
    float z[8], m = -1e30f;
    for (int k = 0; k < 8; k++) {
      z[k] = (sc[t][k] + g64[t * 8 + k]) / tau;
      m = fmaxf(m, z[k]);
    }
    float ssum = 0.f;
    for (int k = 0; k < 8; k++) { z[k] = expf(z[k] - m); ssum += z[k]; }
    for (int k = 0; k < 8; k++) wts[t][k] = z[k] / ssum;
  }
  __syncthreads();
  // F: comb[b][i] = sum_k w * instr
  if (t < 128) {
    const int b = t >> 4, i = t & 15;
    float s = 0.f;
    for (int k = 0; k < 8; k++) s += wts[b][k] * instr[b][k][i];
    comb[b * 16 + i] = s;
  }
}

// ---------------------------------------------------------------------------
// k3: out[b,n,l] = sum_j x[b,n,j] * comb[b][j^l] * SGN[j^l][j]
// grid 2048 blocks x 256 threads, 1 row/thread (4x float4 in, 4x float4 out)
// ---------------------------------------------------------------------------
__global__ __launch_bounds__(256) void k3_apply(
    const float* __restrict__ cpu, const float* __restrict__ comb,
    float* __restrict__ out) {
  const int b = blockIdx.x >> 8;                       // wave-uniform
  const int rowInB = ((blockIdx.x & 255) << 8) + threadIdx.x;
  const size_t row = ((size_t)b << 16) + (size_t)rowInB;

  float cb[16];
  const float* cp = comb + b * 16;
#pragma unroll
  for (int i = 0; i < 16; i++) cb[i] = cp[i];          // uniform -> s_load

  const float4* p = (const float4*)(cpu + row * D_);
  float4 v0 = p[0], v1 = p[1], v2 = p[2], v3 = p[3];
  float x[16] = {v0.x, v0.y, v0.z, v0.w, v1.x, v1.y, v1.z, v1.w,
                 v2.x, v2.y, v2.z, v2.w, v3.x, v3.y, v3.z, v3.w};

  float o[16];
#pragma unroll
  for (int l = 0; l < 16; l++) {
    float acc = 0.f;
#pragma unroll
    for (int j = 0; j < 16; j++) {
      const float s = SGN.v[j ^ l][j];                 // compile-time constant
      if (s > 0.5f)       acc = fmaf(cb[j ^ l], x[j], acc);
      else if (s < -0.5f) acc = fmaf(-cb[j ^ l], x[j], acc);
    }
    o[l] = acc;
  }

  float4* q = (float4*)(out + row * D_);
  q[0] = make_float4(o[0],  o[1],  o[2],  o[3]);
  q[1] = make_float4(o[4],  o[5],  o[6],  o[7]);
  q[2] = make_float4(o[8],  o[9],  o[10], o[11]);
  q[3] = make_float4(o[12], o[13], o[14], o[15]);
}

extern "C" void kernel_launch(void* const* d_in, const int* in_sizes, int n_in,
                              void* d_out, int out_size, void* d_ws, size_t ws_size,
                              hipStream_t stream) {
  const float* cpu       = (const float*)d_in[0];
  const float* ctrl      = (const float*)d_in[1];
  const float* rulemem   = (const float*)d_in[2];
  const float* templates = (const float*)d_in[3];
  const float* W1        = (const float*)d_in[4];
  const float* b1        = (const float*)d_in[5];
  const float* W2        = (const float*)d_in[6];
  const float* b2        = (const float*)d_in[7];
  const float* Wr        = (const float*)d_in[8];
  const float* br        = (const float*)d_in[9];
  const float* logt      = (const float*)d_in[10];

  float* partial = (float*)d_ws;                           // 8*128*16 floats
  float* comb    = partial + (size_t)B_ * BLK_PER_B * 16;  // 128 floats

  k1_reduce<<<dim3(BLK_PER_B, B_), 256, 0, stream>>>(cpu, partial);
  k2_small<<<1, 256, 0, stream>>>(partial, ctrl, rulemem, templates, W1, b1,
                                  W2, b2, Wr, br, logt, comb);
  k3_apply<<<2048, 256, 0, stream>>>(cpu, comb, (float*)d_out);
}

// Round 4
// 117.618 us; speedup vs baseline: 1.0112x; 1.0112x over previous
//
#include <hip/hip_runtime.h>

// ---------------------------------------------------------------------------
// GeometricSuperpositionSearch (all fp32): the reference collapses to
//   new[b,n,l] = sum_j x[b,n,j] * comb[b][j^l] * sign(j^l, j)
// where comb[b] is a single 16-component multivector per batch:
//   comb[b][i] = sum_k weights[b,k] * scores[b,k] * (templates[k,i] + rule_mod[b,k,i])
// k1: reduce cpu_state over N (partial sums)  -> ws
// k2: tiny (1 block): summary, grade norms, MLP, threefry gumbel, softmax,
//     collapse to comb[8][16]                 -> ws
// k3: apply 16x16 signed-permutation operator to every row (memory-bound)
//
// RNG: jax >= 0.4.30 partitionable threefry: element t -> counter (0, t),
// key (0, 42), bits = y0 ^ y1.  (Verified round 3: absmax 3.9e-3.)
// R4 change: k2 phase-A was 128 serially-accumulated scalar loads / thread
// (latency chain ~128 x L2/L3 latency on ONE block). Now: 256 threads x 32
// coalesced loads into compile-time-indexed registers + LDS tree.
// ---------------------------------------------------------------------------

#define B_ 8
#define N_ 65536
#define D_ 16
#define K_ 8
#define M_ 8
#define HID_ 64
#define BLK_PER_B 64                     // k1 blocks per batch
#define ROWS_PER_BLK (N_ / BLK_PER_B)    // 1024 rows -> 4096 float4 per slab

// ---- compile-time Cayley sign table: SGN.v[a][b] = sign of e_a * e_b -> e_{a^b}
struct SgnTab { float v[16][16]; };
constexpr SgnTab make_sgn() {
  SgnTab t{};
  for (int a = 0; a < 16; a++)
    for (int b = 0; b < 16; b++) {
      float s = 1.0f;
      for (int i = 0; i < 4; i++)
        if ((b >> i) & 1) {
          int h = a >> (i + 1), pc = 0;
          for (int q = 0; q < 4; q++) pc += (h >> q) & 1;
          if (pc & 1) s = -s;
          if ((a >> i) & 1) s *= (i == 0 ? 0.0f : 1.0f);  // metric {0,1,1,1}
        }
      t.v[a][b] = s;
    }
  return t;
}
constexpr SgnTab SGN = make_sgn();

// ---- threefry2x32-20, exactly as in jax/_src/prng.py ----
__device__ __forceinline__ unsigned rotl32(unsigned x, int n) {
  return (x << n) | (x >> (32 - n));
}
__device__ void threefry2x32(unsigned k0, unsigned k1, unsigned& x0, unsigned& x1) {
  unsigned ks0 = k0, ks1 = k1, ks2 = k0 ^ k1 ^ 0x1BD11BDAu;
  x0 += ks0; x1 += ks1;
  const int rotA[4] = {13, 15, 26, 6};
  const int rotB[4] = {17, 29, 16, 24};
#define TF_R4(rot)                                      \
  _Pragma("unroll")                                     \
  for (int r = 0; r < 4; r++) {                         \
    x0 += x1; x1 = rotl32(x1, rot[r]); x1 ^= x0;        \
  }
  TF_R4(rotA); x0 += ks1; x1 += ks2 + 1u;
  TF_R4(rotB); x0 += ks2; x1 += ks0 + 2u;
  TF_R4(rotA); x0 += ks0; x1 += ks1 + 3u;
  TF_R4(rotB); x0 += ks1; x1 += ks2 + 4u;
  TF_R4(rotA); x0 += ks2; x1 += ks0 + 5u;
#undef TF_R4
}

// ---------------------------------------------------------------------------
// k1: per-(b,d) partial sums of cpu_state over a 1024-row slab.
// grid (BLK_PER_B, B_), 256 threads; thread t owns component group 4*(t&3)..+3
// ---------------------------------------------------------------------------
__global__ __launch_bounds__(256) void k1_reduce(
    const float* __restrict__ cpu, float* __restrict__ partial) {
  const int b = blockIdx.y, blk = blockIdx.x, t = threadIdx.x;
  const float4* base =
      (const float4*)(cpu + (((size_t)b << 16) + (size_t)blk * ROWS_PER_BLK) * D_);
  float a0 = 0.f, a1 = 0.f, a2 = 0.f, a3 = 0.f;
#pragma unroll
  for (int i = 0; i < (ROWS_PER_BLK * 4) / 256; i++) {   // 16 iters
    float4 v = base[i * 256 + t];
    a0 += v.x; a1 += v.y; a2 += v.z; a3 += v.w;
  }
  __shared__ float red[256 * 4];
  red[t * 4 + 0] = a0; red[t * 4 + 1] = a1;
  red[t * 4 + 2] = a2; red[t * 4 + 3] = a3;
  __syncthreads();
  if (t < 16) {
    const int c = t >> 2, j = t & 3;      // component d = 4c + j
    float s = 0.f;
#pragma unroll
    for (int m = 0; m < 64; m++) s += red[(c + 4 * m) * 4 + j];
    partial[((size_t)b * BLK_PER_B + blk) * 16 + t] = s;
  }
}

// ---------------------------------------------------------------------------
// k2: single block -> comb[8][16] (fp32)
// ---------------------------------------------------------------------------
__global__ __launch_bounds__(256) void k2_small(
    const float* __restrict__ partial,   // [8*64*16] = [8192], flat: b*1024+blk*16+d
    const float* __restrict__ ctrl,      // [8,4]
    const float* __restrict__ rulemem,   // [8,8,16]
    const float* __restrict__ templates, // [8,16]
    const float* __restrict__ W1,        // [9,64]
    const float* __restrict__ b1,        // [64]
    const float* __restrict__ W2,        // [64,8]
    const float* __restrict__ b2,        // [8]
    const float* __restrict__ Wr,        // [16,128]
    const float* __restrict__ br,        // [128]
    const float* __restrict__ logt,      // [1]
    float* __restrict__ comb) {
  const int t = threadIdx.x;
  __shared__ float summary[8][16], rs[8][16], gn[8][5], h[8][64], sc[8][8];
  __shared__ float instr[8][8][16], g64[64], wts[8][8];
  __shared__ float redA[8][16][16];      // [b][seg][d]

  // A: cooperative load+reduce of partial.
  // flat idx = c*256 + t: d = t&15 (fixed), seg = (t>>4), b = idx>>10 == c>>2
  // (exact since t < 256: (c%4)*256 + t < 1024).
  {
    float acc[8];
#pragma unroll
    for (int b = 0; b < 8; b++) acc[b] = 0.f;
#pragma unroll
    for (int c = 0; c < 32; c++)
      acc[c >> 2] += partial[c * 256 + t];   // 32 coalesced, independent loads
#pragma unroll
    for (int b = 0; b < 8; b++) redA[b][t >> 4][t & 15] = acc[b];
  }
  __syncthreads();
  if (t < 128) {
    const int b = t >> 4, d = t & 15;
    float s = 0.f;
#pragma unroll
    for (int g = 0; g < 16; g++) s += redA[b][g][d];
    summary[b][d] = s * (1.0f / (float)N_);
    float rsum = 0.f;
    for (int m = 0; m < M_; m++) rsum += rulemem[(b * M_ + m) * 16 + d];
    rs[b][d] = rsum * (1.0f / (float)M_);
  }
  __syncthreads();
  // B: grade norms
  if (t < 40) {
    const int b = t / 5, g = t % 5;
    float s = 0.f;
    for (int d = 0; d < 16; d++)
      if (__popc(d) == g) { float v = summary[b][d]; s += v * v; }
    gn[b][g] = sqrtf(s + 1e-12f);
  }
  __syncthreads();
  // C1: hidden layer [8][64]
  for (int idx = t; idx < B_ * HID_; idx += 256) {
    const int b = idx >> 6, j = idx & 63;
    float a = b1[j];
    for (int i = 0; i < 9; i++) {
      float in = (i < 5) ? gn[b][i] : ctrl[b * 4 + (i - 5)];
      a += in * W1[i * HID_ + j];
    }
    h[b][j] = fmaxf(a, 0.f);
  }
  __syncthreads();
  // C2: scores [8][8]
  if (t < 64) {
    const int b = t >> 3, k = t & 7;
    float a = b2[k];
    for (int j = 0; j < HID_; j++) a += h[b][j] * W2[j * K_ + k];
    sc[b][k] = a;
  }
  __syncthreads();
  // D: instructions [8][8][16] = scores * (templates + rule_mod)
  for (int idx = t; idx < B_ * K_ * 16; idx += 256) {
    const int b = idx >> 7, k = (idx >> 4) & 7, d = idx & 15;
    float a = br[k * 16 + d];
    for (int j = 0; j < 16; j++) a += rs[b][j] * Wr[j * 128 + k * 16 + d];
    instr[b][k][d] = sc[b][k] * (templates[k * 16 + d] + a);
  }
  // E: gumbel noise — partitionable threefry: counter (0, t), key (0, 42)
  if (t < 64) {
    unsigned x0 = 0u, x1 = (unsigned)t;
    threefry2x32(0u, 42u, x0, x1);
    unsigned bits = x0 ^ x1;
    float f01 = __uint_as_float((bits >> 9) | 0x3f800000u) - 1.0f;
    float u = fmaxf(1e-6f, f01 * (1.0f - 2e-6f) + 1e-6f);
    g64[t] = -logf(-logf(u));
  }
  __syncthreads();
  // weights: softmax((scores+g)/tau)
  if (t < 8) {
    float lt = logt[0];
    float tau = fminf(fmaxf(expf(lt), 0.1f), 5.0f);
    float z[8], m = -1e30f;
    for (int k = 0; k < 8; k++) {
      z[k] = (sc[t][k] + g64[t * 8 + k]) / tau;
      m = fmaxf(m, z[k]);
    }
    float ssum = 0.f;
    for (int k = 0; k < 8; k++) { z[k] = expf(z[k] - m); ssum += z[k]; }
    for (int k = 0; k < 8; k++) wts[t][k] = z[k] / ssum;
  }
  __syncthreads();
  // F: comb[b][i] = sum_k w * instr
  if (t < 128) {
    const int b = t >> 4, i = t & 15;
    float s = 0.f;
    for (int k = 0; k < 8; k++) s += wts[b][k] * instr[b][k][i];
    comb[b * 16 + i] = s;
  }
}

// ---------------------------------------------------------------------------
// k3: out[b,n,l] = sum_j x[b,n,j] * comb[b][j^l] * SGN[j^l][j]
// grid 2048 blocks x 256 threads, 1 row/thread (4x float4 in, 4x float4 out)
// ---------------------------------------------------------------------------
__global__ __launch_bounds__(256) void k3_apply(
    const float* __restrict__ cpu, const float* __restrict__ comb,
    float* __restrict__ out) {
  const int b = blockIdx.x >> 8;                       // wave-uniform
  const int rowInB = ((blockIdx.x & 255) << 8) + threadIdx.x;
  const size_t row = ((size_t)b << 16) + (size_t)rowInB;

  float cb[16];
  const float* cp = comb + b * 16;
#pragma unroll
  for (int i = 0; i < 16; i++) cb[i] = cp[i];          // uniform -> s_load

  const float4* p = (const float4*)(cpu + row * D_);
  float4 v0 = p[0], v1 = p[1], v2 = p[2], v3 = p[3];
  float x[16] = {v0.x, v0.y, v0.z, v0.w, v1.x, v1.y, v1.z, v1.w,
                 v2.x, v2.y, v2.z, v2.w, v3.x, v3.y, v3.z, v3.w};

  float o[16];
#pragma unroll
  for (int l = 0; l < 16; l++) {
    float acc = 0.f;
#pragma unroll
    for (int j = 0; j < 16; j++) {
      const float s = SGN.v[j ^ l][j];                 // compile-time constant
      if (s > 0.5f)       acc = fmaf(cb[j ^ l], x[j], acc);
      else if (s < -0.5f) acc = fmaf(-cb[j ^ l], x[j], acc);
    }
    o[l] = acc;
  }

  float4* q = (float4*)(out + row * D_);
  q[0] = make_float4(o[0],  o[1],  o[2],  o[3]);
  q[1] = make_float4(o[4],  o[5],  o[6],  o[7]);
  q[2] = make_float4(o[8],  o[9],  o[10], o[11]);
  q[3] = make_float4(o[12], o[13], o[14], o[15]);
}

extern "C" void kernel_launch(void* const* d_in, const int* in_sizes, int n_in,
                              void* d_out, int out_size, void* d_ws, size_t ws_size,
                              hipStream_t stream) {
  const float* cpu       = (const float*)d_in[0];
  const float* ctrl      = (const float*)d_in[1];
  const float* rulemem   = (const float*)d_in[2];
  const float* templates = (const float*)d_in[3];
  const float* W1        = (const float*)d_in[4];
  const float* b1        = (const float*)d_in[5];
  const float* W2        = (const float*)d_in[6];
  const float* b2        = (const float*)d_in[7];
  const float* Wr        = (const float*)d_in[8];
  const float* br        = (const float*)d_in[9];
  const float* logt      = (const float*)d_in[10];

  float* partial = (float*)d_ws;                           // 8*64*16 floats
  float* comb    = partial + (size_t)B_ * BLK_PER_B * 16;  // 128 floats

  k1_reduce<<<dim3(BLK_PER_B, B_), 256, 0, stream>>>(cpu, partial);
  k2_small<<<1, 256, 0, stream>>>(partial, ctrl, rulemem, templates, W1, b1,
                                  W2, b2, Wr, br, logt, comb);
  k3_apply<<<2048, 256, 0, stream>>>(cpu, comb, (float*)d_out);
}